// Round 14
// baseline (207.763 us; speedup 1.0000x reference)
//
#include <hip/hip_runtime.h>
#include <stdint.h>

// Problem constants
#define BB 2
#define TT 2048
#define CC 1024
#define NH 16
#define HD 64
#define NG 32              // groups per C row (group size 32)
#define ROWS (BB*TT)       // 4096
#define C3 (3*CC)          // 3072

typedef _Float16 half_t;
typedef __attribute__((ext_vector_type(8))) _Float16 half8;
typedef __attribute__((ext_vector_type(2))) __fp16 fp16x2;
typedef __attribute__((ext_vector_type(4))) float f32x4;
typedef __attribute__((ext_vector_type(16))) float f32x16;

#define GLDS16(g, l) __builtin_amdgcn_global_load_lds( \
    (__attribute__((address_space(1))) void*)(g), \
    (__attribute__((address_space(3))) void*)(l), 16, 0, 0)

#define LOG2E 1.44269504f
#define DEFER_THR 5.5451774f   /* 8 / log2(e) */

__device__ __forceinline__ uint32_t pk_h2(float a, float b) {
  union { fp16x2 h; uint32_t u; } cv;
  cv.h = __builtin_amdgcn_cvt_pkrtz(a, b);
  return cv.u;
}

// ---------------------------------------------------------------------------
// weight fake-quant fp32 -> fp16 dequantized values (both weights, one launch)
// ---------------------------------------------------------------------------
__global__ void k_qdq_w(const float* __restrict__ w1, const float* __restrict__ w2,
                        half_t* __restrict__ o1, half_t* __restrict__ o2) {
  int g = blockIdx.x * blockDim.x + threadIdx.x;
  const float* src; half_t* dst; int gl;
  if (g < C3 * NG) { src = w1; dst = o1; gl = g; }
  else             { src = w2; dst = o2; gl = g - C3 * NG; }
  const float4* p = reinterpret_cast<const float4*>(src + (size_t)gl * 32);
  float v[32]; float amax = 0.f;
  #pragma unroll
  for (int i = 0; i < 8; ++i) {
    float4 t = p[i];
    v[4*i] = t.x; v[4*i+1] = t.y; v[4*i+2] = t.z; v[4*i+3] = t.w;
    amax = fmaxf(amax, fmaxf(fmaxf(fabsf(t.x), fabsf(t.y)), fmaxf(fabsf(t.z), fabsf(t.w))));
  }
  float s = fmaxf(amax / 127.0f, 1e-8f);
  half_t* o = dst + (size_t)gl * 32;
  #pragma unroll
  for (int c = 0; c < 4; ++c) {
    half8 ov;
    #pragma unroll
    for (int jj = 0; jj < 8; ++jj) {
      float q = fminf(fmaxf(rintf(v[c*8+jj] / s), -127.f), 127.f);
      ov[jj] = (half_t)(q * s);
    }
    *reinterpret_cast<half8*>(o + c*8) = ov;
  }
}

// ---------------------------------------------------------------------------
// dequant(qx)+layernorm+fake-quant -> fp16 h. thread per group of 32.
// ---------------------------------------------------------------------------
__global__ void k_qh(const int* __restrict__ qx, const float* __restrict__ sx,
                     const float* __restrict__ mean, const float* __restrict__ rstd,
                     const float* __restrict__ lnw, half_t* __restrict__ h16) {
  int g = blockIdx.x * blockDim.x + threadIdx.x;
  if (g >= ROWS * NG) return;
  int row = g >> 5, grp = g & 31;
  float sxv = sx[g];
  float mu = mean[row], rs = rstd[row];
  const int4* qp = reinterpret_cast<const int4*>(qx + (size_t)row * CC + grp * 32);
  const float4* wp = reinterpret_cast<const float4*>(lnw + grp * 32);
  float v[32]; float amax = 0.f;
  #pragma unroll
  for (int i = 0; i < 8; ++i) {
    int4 qv = qp[i]; float4 wv = wp[i];
    float h0 = ((float)qv.x * sxv - mu) * rs * wv.x;
    float h1 = ((float)qv.y * sxv - mu) * rs * wv.y;
    float h2 = ((float)qv.z * sxv - mu) * rs * wv.z;
    float h3 = ((float)qv.w * sxv - mu) * rs * wv.w;
    v[4*i] = h0; v[4*i+1] = h1; v[4*i+2] = h2; v[4*i+3] = h3;
    amax = fmaxf(amax, fmaxf(fmaxf(fabsf(h0), fabsf(h1)), fmaxf(fabsf(h2), fabsf(h3))));
  }
  float s = fmaxf(amax / 127.0f, 1e-8f);
  half_t* o = h16 + (size_t)row * CC + grp * 32;
  #pragma unroll
  for (int c = 0; c < 4; ++c) {
    half8 ov;
    #pragma unroll
    for (int jj = 0; jj < 8; ++jj) {
      float q = fminf(fmaxf(rintf(v[c*8+jj] / s), -127.f), 127.f);
      ov[jj] = (half_t)(q * s);
    }
    *reinterpret_cast<half8*>(o + c*8) = ov;
  }
}

// ---------------------------------------------------------------------------
// fp16 MFMA GEMM (r11, passing): 128x128 tile, BK=32 double-buffered,
// XCD-bijective swizzle, split-K via blockIdx.z.
// ---------------------------------------------------------------------------
template<typename TO>
__global__ __launch_bounds__(256) void k_gemm16(const half_t* __restrict__ A,
                                                const half_t* __restrict__ B,
                                                TO* __restrict__ Out, int N,
                                                int gx, int cpx, int klen) {
  __shared__ __align__(16) half_t As[2][128*32];
  __shared__ __align__(16) half_t Bs[2][128*32];
  const int tid = threadIdx.x;
  const int wave = tid >> 6, lane = tid & 63;
  const int l15 = lane & 15, lg = lane >> 4;
  const int flat = blockIdx.y * gx + blockIdx.x;
  const int swz = (flat & 7) * cpx + (flat >> 3);
  const int m0 = (swz / gx) * 128, n0 = (swz % gx) * 128;
  const int kbeg = blockIdx.z * klen;
  TO* out = Out + (size_t)blockIdx.z * ROWS * N;
  const int wm = (wave >> 1) * 64, wn = (wave & 1) * 64;
  f32x4 acc[4][4];
  #pragma unroll
  for (int i = 0; i < 4; ++i)
    #pragma unroll
    for (int jj = 0; jj < 4; ++jj) acc[i][jj] = f32x4{0.f, 0.f, 0.f, 0.f};
  const int srow = lane >> 2;
  const int scol = (lane & 3) * 8;
  const int seg0 = wave * 2;
  auto stage = [&](int buf, int k0) {
    #pragma unroll
    for (int s = 0; s < 2; ++s) {
      const int seg = seg0 + s;
      GLDS16(A + (size_t)(m0 + seg*16 + srow) * 1024 + k0 + scol, &As[buf][0] + seg*512);
      GLDS16(B + (size_t)(n0 + seg*16 + srow) * 1024 + k0 + scol, &Bs[buf][0] + seg*512);
    }
  };
  stage(0, kbeg);
  __syncthreads();
  int cur = 0;
  for (int k0 = kbeg; k0 < kbeg + klen; k0 += 32) {
    if (k0 + 32 < kbeg + klen) stage(cur ^ 1, k0 + 32);
    half8 af[4], bf[4];
    #pragma unroll
    for (int i = 0; i < 4; ++i) {
      af[i] = *reinterpret_cast<const half8*>(&As[cur][0] + (wm + i*16 + l15)*32 + lg*8);
      bf[i] = *reinterpret_cast<const half8*>(&Bs[cur][0] + (wn + i*16 + l15)*32 + lg*8);
    }
    #pragma unroll
    for (int mi = 0; mi < 4; ++mi)
      #pragma unroll
      for (int ni = 0; ni < 4; ++ni)
        acc[mi][ni] = __builtin_amdgcn_mfma_f32_16x16x32_f16(af[mi], bf[ni], acc[mi][ni], 0, 0, 0);
    __syncthreads();
    cur ^= 1;
  }
  const int crow = m0 + wm + lg * 4;
  const int ccol = n0 + wn + l15;
  #pragma unroll
  for (int mi = 0; mi < 4; ++mi)
    #pragma unroll
    for (int ni = 0; ni < 4; ++ni)
      #pragma unroll
      for (int r = 0; r < 4; ++r)
        out[(size_t)(crow + mi*16 + r) * N + ccol + ni*16] = (TO)acc[mi][ni][r];
}

// ---------------------------------------------------------------------------
// MFMA flash attention, 32x32x16, in-reg P, CONTIGUOUS KEY STREAMS.
// grid (B*NH, 16), 512 thr / 8 waves. Block j owns tiles {j, 31-j} (33 kt
// units) partitioned into 4 contiguous-key streams. Wave = (stream, rowhalf).
// All 8 waves compute every iteration against their own single-buffered
// stream K/V (4 x 18KB = 72KB -> 2 blocks/CU). Group g (128 thr) stages
// stream g's tile (reg-prefetched). Stream partials merged via LDS at end.
// r13 bug fixed: K staging now covers ALL 32 dims/thread (4 x uint4 at
// half-offsets 0/8/16/24 — r13 loaded only 0 and 16, leaving dims 8..15
// and 24..31 of every key stale).
// ---------------------------------------------------------------------------
__global__ __launch_bounds__(512, 4) void k_attn32(const half_t* __restrict__ qkv,
                                                   half_t* __restrict__ y16) {
  __shared__ __align__(16) half_t smem[4 * 2 * 4608];  // per stream: K(64*72) + Vt(64*72)
  const int tid = threadIdx.x;
  const int wave = tid >> 6, lane = tid & 63;
  const int l31 = lane & 31, lh = lane >> 5;
  const int bh = blockIdx.x, b = bh >> 4, h = bh & 15;
  const int j = blockIdx.y;
  const int nA = j + 1, nB = 32 - j;

  // stream partition: kA streams for tile A minimizing max length
  int kA = 1, maxlen = 1 << 30;
  #pragma unroll
  for (int k = 1; k <= 3; ++k) {
    const int l1 = (nA + k - 1) / k;
    const int l2 = (nB + (3 - k)) / (4 - k);
    const int mx = l1 > l2 ? l1 : l2;
    if (mx < maxlen) { maxlen = mx; kA = k; }
  }
  auto sdesc = [&](int s, int& base, int& len, int& sqt) {
    const int tB = (s >= kA);
    const int n = tB ? nB : nA;
    const int k = tB ? (4 - kA) : kA;
    const int i = tB ? (s - kA) : s;
    const int q = n / k, r = n % k;
    base = i * q + (i < r ? i : r);
    len = q + (i < r ? 1 : 0);
    sqt = tB ? (31 - j) : j;
  };

  const int sid = wave >> 1, rh = wave & 1;
  int wbase, wlen, wqt;
  sdesc(sid, wbase, wlen, wqt);

  // Q fragments: qreg[kk][i] = Q[qrow][kk*16 + lh*8 + i] * 0.125
  const size_t qrow = (size_t)(b * TT + wqt * 64 + rh * 32 + l31);
  const half_t* qp = qkv + qrow * C3 + h * HD + lh * 8;
  half8 qreg[4];
  #pragma unroll
  for (int kk = 0; kk < 4; ++kk)
    qreg[kk] = *reinterpret_cast<const half8*>(qp + kk * 16) * (half_t)0.125f;

  float m = -3.0e38f, lsum = 0.f;
  f32x16 yacc[2];
  yacc[0] = (f32x16)(0.f); yacc[1] = (f32x16)(0.f);

  // V^T read granule bases (dword index before XOR), per db  (r12-verified)
  int vbase[2], vxr[2];
  #pragma unroll
  for (int db = 0; db < 2; ++db) {
    const int d = db * 32 + l31;
    vbase[db] = d * 36 + lh * 4;
    vxr[db] = ((d >> 3) & 7) << 2;
  }

  // staging: group g (=sid of its waves) stages stream g's tile
  const int g = tid >> 7, t128 = tid & 127;
  int gbase, glen, gqt_;
  sdesc(g, gbase, glen, gqt_);
  const int skey = t128 >> 1, sch = (t128 & 1) * 32;   // K: key, 32-dim half (halves)
  const int vkp = t128 >> 2, vd0 = (t128 & 3) * 16;    // V: key pair, 16 dims
  const int csp = (vkp & 0x19) | ((vkp & 2) << 1) | ((vkp & 4) >> 1);  // key b2<->b3 swap

  uint4 kr0, kr1, kr2, kr3, v0a, v0b, v1a, v1b;
  const half_t* kvb = qkv + ((size_t)b * TT) * C3 + CC + h * HD;
  auto kload = [&](int kt) {
    const half_t* kp = kvb + (size_t)(kt*64 + skey) * C3 + sch;
    kr0 = *reinterpret_cast<const uint4*>(kp);          // dims sch+0..7
    kr1 = *reinterpret_cast<const uint4*>(kp + 8);      // dims sch+8..15
    kr2 = *reinterpret_cast<const uint4*>(kp + 16);     // dims sch+16..23
    kr3 = *reinterpret_cast<const uint4*>(kp + 24);     // dims sch+24..31
    const half_t* vp = kvb + (size_t)(kt*64 + vkp*2) * C3 + CC + vd0;
    v0a = *reinterpret_cast<const uint4*>(vp);
    v0b = *reinterpret_cast<const uint4*>(vp + 8);
    v1a = *reinterpret_cast<const uint4*>(vp + C3);
    v1b = *reinterpret_cast<const uint4*>(vp + C3 + 8);
  };
  auto stage = [&]() {
    half_t* ks = smem + g * 9216;
    *reinterpret_cast<uint4*>(ks + skey*72 + sch)      = kr0;
    *reinterpret_cast<uint4*>(ks + skey*72 + sch + 8)  = kr1;
    *reinterpret_cast<uint4*>(ks + skey*72 + sch + 16) = kr2;
    *reinterpret_cast<uint4*>(ks + skey*72 + sch + 24) = kr3;
    uint32_t* vt = reinterpret_cast<uint32_t*>(ks + 4608);
    const uint32_t w0[8] = {v0a.x, v0a.y, v0a.z, v0a.w, v0b.x, v0b.y, v0b.z, v0b.w};
    const uint32_t w1[8] = {v1a.x, v1a.y, v1a.z, v1a.w, v1b.x, v1b.y, v1b.z, v1b.w};
    #pragma unroll
    for (int i = 0; i < 8; ++i) {
      const int d = vd0 + 2*i;
      const int x = ((d >> 3) & 7) << 2;   // d even: d,d+1 share group
      vt[(d*36 + csp) ^ x]       = __builtin_amdgcn_perm(w1[i], w0[i], 0x05040100u);
      vt[((d+1)*36 + csp) ^ x]   = __builtin_amdgcn_perm(w1[i], w0[i], 0x07060302u);
    }
  };

  kload(gbase);                 // glen >= 1 always
  for (int t = 0; t < maxlen; ++t) {
    __syncthreads();            // previous compute done; buffers reusable
    if (t < glen) stage();
    __syncthreads();            // staged visible
    if (t + 1 < glen) kload(gbase + t + 1);   // prefetch under compute
    if (t < wlen) {
      const int kt = wbase + t;
      const half_t* ksb = smem + sid * 9216;
      const uint32_t* vt32 = reinterpret_cast<const uint32_t*>(ksb + 4608);
      // ---- QK^T: S^T[key 0..63][q = l31] ----
      f32x16 sacc[2];
      sacc[0] = (f32x16)(0.f); sacc[1] = (f32x16)(0.f);
      __builtin_amdgcn_s_setprio(1);
      #pragma unroll
      for (int kb = 0; kb < 2; ++kb)
        #pragma unroll
        for (int kk = 0; kk < 4; ++kk) {
          const half8 a = *reinterpret_cast<const half8*>(
              ksb + (kb*32 + l31)*72 + kk*16 + lh*8);
          sacc[kb] = __builtin_amdgcn_mfma_f32_32x32x16_f16(a, qreg[kk], sacc[kb], 0, 0, 0);
        }
      __builtin_amdgcn_s_setprio(0);
      // ---- softmax (keys in regs: key = kb*32 + (r&3)+8*(r>>2)+4*lh) ----
      float sv[2][16]; float tm = -3.0e38f;
      const bool diag = (kt == wqt);
      const int qloc = rh * 32 + l31;
      #pragma unroll
      for (int kb = 0; kb < 2; ++kb)
        #pragma unroll
        for (int r = 0; r < 16; ++r) {
          float s = sacc[kb][r];
          if (diag && (kb*32 + (r&3) + 8*(r>>2) + 4*lh > qloc)) s = -1e30f;
          sv[kb][r] = s;
          tm = fmaxf(tm, s);
        }
      tm = fmaxf(tm, __shfl_xor(tm, 32));
      if (!__all(tm <= m + DEFER_THR)) {
        const float mn = fmaxf(m, tm);
        const float alpha = __builtin_amdgcn_exp2f((m - mn) * LOG2E);
        yacc[0] *= alpha; yacc[1] *= alpha;
        lsum *= alpha;
        m = mn;
      }
      const float nm = -m * LOG2E;
      float rs = 0.f;
      #pragma unroll
      for (int kb = 0; kb < 2; ++kb)
        #pragma unroll
        for (int r = 0; r < 16; ++r) {
          sv[kb][r] = __builtin_amdgcn_exp2f(fmaf(sv[kb][r], LOG2E, nm));
          rs += sv[kb][r];
        }
      lsum += rs;
      // ---- pack P in-register ----
      uint32_t w[2][8];
      #pragma unroll
      for (int kb = 0; kb < 2; ++kb)
        #pragma unroll
        for (int r2 = 0; r2 < 8; ++r2)
          w[kb][r2] = pk_h2(sv[kb][2*r2], sv[kb][2*r2+1]);
      // ---- PV: yacc[db] += V^T[db] . P (B-frag = own regs, no LDS) ----
      __builtin_amdgcn_s_setprio(1);
      #pragma unroll
      for (int db = 0; db < 2; ++db)
        #pragma unroll
        for (int kb = 0; kb < 2; ++kb)
          #pragma unroll
          for (int kk = 0; kk < 2; ++kk) {
            const int gdw = (vbase[db] + kb*16 + kk*8) ^ vxr[db];
            const half8 va = *reinterpret_cast<const half8*>(vt32 + gdw);
            union { uint32_t u[4]; half8 h; } bf;
            bf.u[0] = w[kb][4*kk + 0]; bf.u[1] = w[kb][4*kk + 1];
            bf.u[2] = w[kb][4*kk + 2]; bf.u[3] = w[kb][4*kk + 3];
            yacc[db] = __builtin_amdgcn_mfma_f32_32x32x16_f16(va, bf.h, yacc[db], 0, 0, 0);
          }
      __builtin_amdgcn_s_setprio(0);
    }
  }

  // ---- merge stream partials per tile through LDS (K/V buffers dead) ----
  __syncthreads();   // all compute done before aliasing smem
  float* mb = reinterpret_cast<float*>(smem);
  float* yb = mb + wave * 2176;
  #pragma unroll
  for (int db = 0; db < 2; ++db)
    #pragma unroll
    for (int r = 0; r < 16; ++r)
      yb[(db*16 + r) * 64 + lane] = yacc[db][r];
  yb[2048 + lane] = m;
  yb[2112 + lane] = lsum;
  __syncthreads();
  const bool ismg = (sid == 0) || (sid == kA);
  if (ismg) {
    const int s0 = (sid == 0) ? 0 : kA;
    const int sn = (sid == 0) ? kA : (4 - kA);
    float M = m;
    for (int s = 1; s < sn; ++s)
      M = fmaxf(M, mb[((s0 + s)*2 + rh)*2176 + 2048 + lane]);
    const float a0 = __builtin_amdgcn_exp2f((m - M) * LOG2E);
    float lh_ = lsum * a0;
    float yv[2][16];
    #pragma unroll
    for (int db = 0; db < 2; ++db)
      #pragma unroll
      for (int r = 0; r < 16; ++r) yv[db][r] = yacc[db][r] * a0;
    for (int s = 1; s < sn; ++s) {
      float* pb = mb + ((s0 + s)*2 + rh)*2176;
      const float as = __builtin_amdgcn_exp2f((pb[2048 + lane] - M) * LOG2E);
      lh_ += pb[2112 + lane] * as;
      #pragma unroll
      for (int db = 0; db < 2; ++db)
        #pragma unroll
        for (int r = 0; r < 16; ++r)
          yv[db][r] += pb[(db*16 + r) * 64 + lane] * as;
    }
    float lt = lh_ + __shfl_xor(lh_, 32);
    const float inv = 1.0f / lt;
    #pragma unroll
    for (int db = 0; db < 2; ++db)
      #pragma unroll
      for (int r = 0; r < 16; ++r) yv[db][r] *= inv;
    // epilogue: per-db (=32-dim group) fake-quant, write fp16 qdq values
    half_t* yp = y16 + qrow * CC + h * HD;
    #pragma unroll
    for (int db = 0; db < 2; ++db) {
      float am = 0.f;
      #pragma unroll
      for (int r = 0; r < 16; ++r) am = fmaxf(am, fabsf(yv[db][r]));
      am = fmaxf(am, __shfl_xor(am, 32));
      const float s = fmaxf(am / 127.0f, 1e-8f);
      const float qi = 1.0f / s;
      #pragma unroll
      for (int t = 0; t < 4; ++t) {
        union { half_t h4[4]; uint64_t u; } pk;
        #pragma unroll
        for (int rr = 0; rr < 4; ++rr) {
          float q = fminf(fmaxf(rintf(yv[db][4*t + rr] * qi), -127.f), 127.f);
          pk.h4[rr] = (half_t)(q * s);
        }
        *reinterpret_cast<uint64_t*>(yp + db*32 + 8*t + 4*lh) = pk.u;
      }
    }
  }
}

// ---------------------------------------------------------------------------
// residual (x + proj_part0 + proj_part1) + stats + output quantization.
// ---------------------------------------------------------------------------
__global__ __launch_bounds__(256) void k_final(
    const float* __restrict__ x, const half_t* __restrict__ p0,
    const half_t* __restrict__ p1,
    float* __restrict__ out_fpx, float* __restrict__ out_qo, float* __restrict__ out_so,
    float* __restrict__ out_mean, float* __restrict__ out_rstd) {
  __shared__ float red[16];
  int row = blockIdx.x;
  int tid = threadIdx.x;
  size_t base = (size_t)row * CC + tid * 4;
  float4 xv = *reinterpret_cast<const float4*>(x + base);
  union { uint64_t u; half_t h[4]; } pa, pb;
  pa.u = *reinterpret_cast<const uint64_t*>(p0 + base);
  pb.u = *reinterpret_cast<const uint64_t*>(p1 + base);
  float4 f;
  f.x = xv.x + (float)pa.h[0] + (float)pb.h[0];
  f.y = xv.y + (float)pa.h[1] + (float)pb.h[1];
  f.z = xv.z + (float)pa.h[2] + (float)pb.h[2];
  f.w = xv.w + (float)pa.h[3] + (float)pb.h[3];
  *reinterpret_cast<float4*>(out_fpx + base) = f;
  float sum = f.x + f.y + f.z + f.w;
  float sq  = f.x*f.x + f.y*f.y + f.z*f.z + f.w*f.w;
  #pragma unroll
  for (int off = 1; off < 64; off <<= 1) {
    sum += __shfl_xor(sum, off);
    sq  += __shfl_xor(sq, off);
  }
  int wid = tid >> 6, lane = tid & 63;
  if (lane == 0) { red[wid] = sum; red[8 + wid] = sq; }
  __syncthreads();
  if (tid == 0) {
    float s4 = red[0] + red[1] + red[2] + red[3];
    float q4 = red[8] + red[9] + red[10] + red[11];
    float mu = s4 * (1.0f / CC);
    float var = q4 * (1.0f / CC) - mu * mu;
    out_mean[row] = mu;
    out_rstd[row] = 1.0f / sqrtf(var + 1e-5f);
  }
  float amax = fmaxf(fmaxf(fabsf(f.x), fabsf(f.y)), fmaxf(fabsf(f.z), fabsf(f.w)));
  #pragma unroll
  for (int off = 1; off < 8; off <<= 1) amax = fmaxf(amax, __shfl_xor(amax, off, 8));
  float s = fmaxf(amax / 127.0f, 1e-8f);
  int g = tid >> 3, li = tid & 7;
  if (li == 0) out_so[row * NG + g] = s;
  float4 qo;
  qo.x = fminf(fmaxf(rintf(f.x / s), -127.f), 127.f);
  qo.y = fminf(fmaxf(rintf(f.y / s), -127.f), 127.f);
  qo.z = fminf(fmaxf(rintf(f.z / s), -127.f), 127.f);
  qo.w = fminf(fmaxf(rintf(f.w / s), -127.f), 127.f);
  *reinterpret_cast<float4*>(out_qo + base) = qo;
}

// ---------------------------------------------------------------------------
extern "C" void kernel_launch(void* const* d_in, const int* in_sizes, int n_in,
                              void* d_out, int out_size, void* d_ws, size_t ws_size,
                              hipStream_t stream) {
  const float* x    = (const float*)d_in[0];
  const int*   qx   = (const int*)d_in[1];
  const float* sx   = (const float*)d_in[2];
  const float* mean = (const float*)d_in[3];
  const float* rstd = (const float*)d_in[4];
  const float* lnw  = (const float*)d_in[5];
  const float* w1   = (const float*)d_in[6];
  const float* w2   = (const float*)d_in[7];

  float* out = (float*)d_out;
  float* o_fpx  = out;
  float* o_qo   = o_fpx + (size_t)ROWS * CC;
  float* o_so   = o_qo  + (size_t)ROWS * CC;
  float* o_mean = o_so  + (size_t)ROWS * NG;
  float* o_rstd = o_mean + ROWS;

  size_t off = 0;
  char* wsb = (char*)d_ws;
  auto alloc = [&](size_t bytes) -> void* {
    void* p = wsb + off;
    off += (bytes + 255) & ~(size_t)255;
    return p;
  };
  half_t* h16   = (half_t*)alloc((size_t)ROWS * CC * 2);
  half_t* w116  = (half_t*)alloc((size_t)C3 * CC * 2);
  half_t* w216  = (half_t*)alloc((size_t)CC * CC * 2);
  half_t* qkv16 = (half_t*)alloc((size_t)ROWS * C3 * 2);
  half_t* y16   = (half_t*)alloc((size_t)ROWS * CC * 2);
  half_t* proj  = (half_t*)alloc((size_t)2 * ROWS * CC * 2);   // 2 K-slices

  // 1. weight fake-quant -> fp16 (both weights, one launch)
  k_qdq_w<<<(C3 * NG + CC * NG) / 256, 256, 0, stream>>>(w1, w2, w116, w216);
  // 2. LN + activation fake-quant -> fp16
  k_qh<<<(ROWS * NG) / 256, 256, 0, stream>>>(qx, sx, mean, rstd, lnw, h16);
  // 3. qkv = h @ w1^T  (fp16 MFMA, dbuf 2-phase, XCD-swizzled)
  k_gemm16<half_t><<<dim3(C3 / 128, ROWS / 128, 1), 256, 0, stream>>>(
      h16, w116, qkv16, C3, C3 / 128, (C3 / 128) * (ROWS / 128) / 8, 1024);
  // 4. causal SDPA (32x32 MFMA, in-reg P, contiguous key streams)
  k_attn32<<<dim3(BB * NH, 16), 512, 0, stream>>>(qkv16, y16);
  // 5. proj = y @ w2^T  (fp16 MFMA, dbuf 2-phase, split-K=2)
  k_gemm16<half_t><<<dim3(CC / 128, ROWS / 128, 2), 256, 0, stream>>>(
      y16, w216, proj, CC, CC / 128, (CC / 128) * (ROWS / 128) / 8, 512);
  // 6. residual (x + p0 + p1) + stats + output quant
  k_final<<<ROWS, 256, 0, stream>>>(x, proj, proj + (size_t)ROWS * CC,
                                    o_fpx, o_qo, o_so, o_mean, o_rstd);
}

// Round 15
// 156.845 us; speedup vs baseline: 1.3246x; 1.3246x over previous
//
#include <hip/hip_runtime.h>
#include <stdint.h>

// Problem constants
#define BB 2
#define TT 2048
#define CC 1024
#define NH 16
#define HD 64
#define NG 32              // groups per C row (group size 32)
#define ROWS (BB*TT)       // 4096
#define C3 (3*CC)          // 3072

typedef _Float16 half_t;
typedef __attribute__((ext_vector_type(8))) _Float16 half8;
typedef __attribute__((ext_vector_type(2))) __fp16 fp16x2;
typedef __attribute__((ext_vector_type(4))) float f32x4;
typedef __attribute__((ext_vector_type(16))) float f32x16;

#define GLDS16(g, l) __builtin_amdgcn_global_load_lds( \
    (__attribute__((address_space(1))) void*)(g), \
    (__attribute__((address_space(3))) void*)(l), 16, 0, 0)

#define LOG2E 1.44269504f
#define DEFER_THR 5.5451774f   /* 8 / log2(e) */

__device__ __forceinline__ uint32_t pk_h2(float a, float b) {
  union { fp16x2 h; uint32_t u; } cv;
  cv.h = __builtin_amdgcn_cvt_pkrtz(a, b);
  return cv.u;
}

// ---------------------------------------------------------------------------
// weight fake-quant fp32 -> fp16 dequantized values (both weights, one launch)
// ---------------------------------------------------------------------------
__global__ void k_qdq_w(const float* __restrict__ w1, const float* __restrict__ w2,
                        half_t* __restrict__ o1, half_t* __restrict__ o2) {
  int g = blockIdx.x * blockDim.x + threadIdx.x;
  const float* src; half_t* dst; int gl;
  if (g < C3 * NG) { src = w1; dst = o1; gl = g; }
  else             { src = w2; dst = o2; gl = g - C3 * NG; }
  const float4* p = reinterpret_cast<const float4*>(src + (size_t)gl * 32);
  float v[32]; float amax = 0.f;
  #pragma unroll
  for (int i = 0; i < 8; ++i) {
    float4 t = p[i];
    v[4*i] = t.x; v[4*i+1] = t.y; v[4*i+2] = t.z; v[4*i+3] = t.w;
    amax = fmaxf(amax, fmaxf(fmaxf(fabsf(t.x), fabsf(t.y)), fmaxf(fabsf(t.z), fabsf(t.w))));
  }
  float s = fmaxf(amax / 127.0f, 1e-8f);
  half_t* o = dst + (size_t)gl * 32;
  #pragma unroll
  for (int c = 0; c < 4; ++c) {
    half8 ov;
    #pragma unroll
    for (int jj = 0; jj < 8; ++jj) {
      float q = fminf(fmaxf(rintf(v[c*8+jj] / s), -127.f), 127.f);
      ov[jj] = (half_t)(q * s);
    }
    *reinterpret_cast<half8*>(o + c*8) = ov;
  }
}

// ---------------------------------------------------------------------------
// dequant(qx)+layernorm+fake-quant -> fp16 h. thread per group of 32.
// ---------------------------------------------------------------------------
__global__ void k_qh(const int* __restrict__ qx, const float* __restrict__ sx,
                     const float* __restrict__ mean, const float* __restrict__ rstd,
                     const float* __restrict__ lnw, half_t* __restrict__ h16) {
  int g = blockIdx.x * blockDim.x + threadIdx.x;
  if (g >= ROWS * NG) return;
  int row = g >> 5, grp = g & 31;
  float sxv = sx[g];
  float mu = mean[row], rs = rstd[row];
  const int4* qp = reinterpret_cast<const int4*>(qx + (size_t)row * CC + grp * 32);
  const float4* wp = reinterpret_cast<const float4*>(lnw + grp * 32);
  float v[32]; float amax = 0.f;
  #pragma unroll
  for (int i = 0; i < 8; ++i) {
    int4 qv = qp[i]; float4 wv = wp[i];
    float h0 = ((float)qv.x * sxv - mu) * rs * wv.x;
    float h1 = ((float)qv.y * sxv - mu) * rs * wv.y;
    float h2 = ((float)qv.z * sxv - mu) * rs * wv.z;
    float h3 = ((float)qv.w * sxv - mu) * rs * wv.w;
    v[4*i] = h0; v[4*i+1] = h1; v[4*i+2] = h2; v[4*i+3] = h3;
    amax = fmaxf(amax, fmaxf(fmaxf(fabsf(h0), fabsf(h1)), fmaxf(fabsf(h2), fabsf(h3))));
  }
  float s = fmaxf(amax / 127.0f, 1e-8f);
  half_t* o = h16 + (size_t)row * CC + grp * 32;
  #pragma unroll
  for (int c = 0; c < 4; ++c) {
    half8 ov;
    #pragma unroll
    for (int jj = 0; jj < 8; ++jj) {
      float q = fminf(fmaxf(rintf(v[c*8+jj] / s), -127.f), 127.f);
      ov[jj] = (half_t)(q * s);
    }
    *reinterpret_cast<half8*>(o + c*8) = ov;
  }
}

// ---------------------------------------------------------------------------
// fp16 MFMA GEMM (r11, passing): 128x128 tile, BK=32 double-buffered,
// XCD-bijective swizzle, split-K via blockIdx.z.
// ---------------------------------------------------------------------------
template<typename TO>
__global__ __launch_bounds__(256) void k_gemm16(const half_t* __restrict__ A,
                                                const half_t* __restrict__ B,
                                                TO* __restrict__ Out, int N,
                                                int gx, int cpx, int klen) {
  __shared__ __align__(16) half_t As[2][128*32];
  __shared__ __align__(16) half_t Bs[2][128*32];
  const int tid = threadIdx.x;
  const int wave = tid >> 6, lane = tid & 63;
  const int l15 = lane & 15, lg = lane >> 4;
  const int flat = blockIdx.y * gx + blockIdx.x;
  const int swz = (flat & 7) * cpx + (flat >> 3);
  const int m0 = (swz / gx) * 128, n0 = (swz % gx) * 128;
  const int kbeg = blockIdx.z * klen;
  TO* out = Out + (size_t)blockIdx.z * ROWS * N;
  const int wm = (wave >> 1) * 64, wn = (wave & 1) * 64;
  f32x4 acc[4][4];
  #pragma unroll
  for (int i = 0; i < 4; ++i)
    #pragma unroll
    for (int jj = 0; jj < 4; ++jj) acc[i][jj] = f32x4{0.f, 0.f, 0.f, 0.f};
  const int srow = lane >> 2;
  const int scol = (lane & 3) * 8;
  const int seg0 = wave * 2;
  auto stage = [&](int buf, int k0) {
    #pragma unroll
    for (int s = 0; s < 2; ++s) {
      const int seg = seg0 + s;
      GLDS16(A + (size_t)(m0 + seg*16 + srow) * 1024 + k0 + scol, &As[buf][0] + seg*512);
      GLDS16(B + (size_t)(n0 + seg*16 + srow) * 1024 + k0 + scol, &Bs[buf][0] + seg*512);
    }
  };
  stage(0, kbeg);
  __syncthreads();
  int cur = 0;
  for (int k0 = kbeg; k0 < kbeg + klen; k0 += 32) {
    if (k0 + 32 < kbeg + klen) stage(cur ^ 1, k0 + 32);
    half8 af[4], bf[4];
    #pragma unroll
    for (int i = 0; i < 4; ++i) {
      af[i] = *reinterpret_cast<const half8*>(&As[cur][0] + (wm + i*16 + l15)*32 + lg*8);
      bf[i] = *reinterpret_cast<const half8*>(&Bs[cur][0] + (wn + i*16 + l15)*32 + lg*8);
    }
    #pragma unroll
    for (int mi = 0; mi < 4; ++mi)
      #pragma unroll
      for (int ni = 0; ni < 4; ++ni)
        acc[mi][ni] = __builtin_amdgcn_mfma_f32_16x16x32_f16(af[mi], bf[ni], acc[mi][ni], 0, 0, 0);
    __syncthreads();
    cur ^= 1;
  }
  const int crow = m0 + wm + lg * 4;
  const int ccol = n0 + wn + l15;
  #pragma unroll
  for (int mi = 0; mi < 4; ++mi)
    #pragma unroll
    for (int ni = 0; ni < 4; ++ni)
      #pragma unroll
      for (int r = 0; r < 4; ++r)
        out[(size_t)(crow + mi*16 + r) * N + ccol + ni*16] = (TO)acc[mi][ni][r];
}

// ---------------------------------------------------------------------------
// MFMA flash attention, 32x32x16, in-reg P, TWO TILES PER EPOCH.
// grid (B*NH, 16), 512 thr / 8 waves. Block j owns tiles {j, 31-j};
// kt walks 0,1,2,... SEQUENTIALLY (L2-friendly, the r14 lesson).
// wave = (tile=w>>2, par=(w>>1)&1, rowhalf=w&1): parity-p wave computes
// tile kt=2e+p each epoch -> ALL 8 waves active every epoch.
// 4 K/V buffers (2 epochs); epoch e stages tiles {2e+2,2e+3} under compute.
// 512 threads stage 2 tiles (ts=tid>>8), only 16 staging VGPRs (r14 lesson).
// Compute/mask/V-swizzle/merge/epilogue = r12/r14-verified code, verbatim.
// ---------------------------------------------------------------------------
__global__ __launch_bounds__(512, 4) void k_attn32(const half_t* __restrict__ qkv,
                                                   half_t* __restrict__ y16) {
  __shared__ __align__(16) half_t smem[4][9216];  // [buf]: K 64*72 | Vt 64*72
  const int tid = threadIdx.x;
  const int wave = tid >> 6, lane = tid & 63;
  const int l31 = lane & 31, lh = lane >> 5;
  const int bh = blockIdx.x, b = bh >> 4, h = bh & 15;
  const int j = blockIdx.y;                 // 0..15
  const int tile = wave >> 2, par = (wave >> 1) & 1, rh = wave & 1;
  const int qt = tile ? (31 - j) : j;
  const int ktmax = 31 - j;                 // >= 16
  const int E = (ktmax >> 1) + 1;           // epochs

  // Q fragments: qreg[kk][i] = Q[qrow][kk*16 + lh*8 + i] * 0.125
  const size_t qrow = (size_t)(b * TT + qt * 64 + rh * 32 + l31);
  const half_t* qp = qkv + qrow * C3 + h * HD + lh * 8;
  half8 qreg[4];
  #pragma unroll
  for (int kk = 0; kk < 4; ++kk)
    qreg[kk] = *reinterpret_cast<const half8*>(qp + kk * 16) * (half_t)0.125f;

  float m = -3.0e38f, lsum = 0.f;
  f32x16 yacc[2];
  yacc[0] = (f32x16)(0.f); yacc[1] = (f32x16)(0.f);

  // V^T read granule bases (dword index before XOR), per db  (r12-verified)
  int vbase[2], vxr[2];
  #pragma unroll
  for (int db = 0; db < 2; ++db) {
    const int d = db * 32 + l31;
    vbase[db] = d * 36 + lh * 4;
    vxr[db] = ((d >> 3) & 7) << 2;
  }

  // staging maps: ts = which of the epoch's two tiles; 256 threads per tile
  const int ts = tid >> 8, t256 = tid & 255;
  const int skey = t256 >> 2, sch = (t256 & 3) * 16;   // K: key, 16-half chunk
  const int vkp = t256 >> 3, vd0 = (t256 & 7) * 8;     // V: key pair, 8 dims
  const int csp = (vkp & 0x19) | ((vkp & 2) << 1) | ((vkp & 4) >> 1);  // key b2<->b3

  uint4 kr0, kr1, v0r, v1r;   // 16 staging VGPRs total
  const half_t* kvb = qkv + ((size_t)b * TT) * C3 + CC + h * HD;
  auto kload = [&](int kt) {
    const half_t* kp = kvb + (size_t)(kt*64 + skey) * C3 + sch;
    kr0 = *reinterpret_cast<const uint4*>(kp);       // dims sch..sch+7
    kr1 = *reinterpret_cast<const uint4*>(kp + 8);   // dims sch+8..sch+15
    const half_t* vp = kvb + (size_t)(kt*64 + vkp*2) * C3 + CC + vd0;
    v0r = *reinterpret_cast<const uint4*>(vp);
    v1r = *reinterpret_cast<const uint4*>(vp + C3);
  };
  auto stage = [&](int buf) {
    half_t* ks = &smem[buf][0];
    *reinterpret_cast<uint4*>(ks + skey*72 + sch)     = kr0;
    *reinterpret_cast<uint4*>(ks + skey*72 + sch + 8) = kr1;
    uint32_t* vt = reinterpret_cast<uint32_t*>(ks + 4608);
    const uint32_t w0[4] = {v0r.x, v0r.y, v0r.z, v0r.w};
    const uint32_t w1[4] = {v1r.x, v1r.y, v1r.z, v1r.w};
    #pragma unroll
    for (int i = 0; i < 4; ++i) {
      const int d = vd0 + 2*i;
      const int x = ((d >> 3) & 7) << 2;
      vt[(d*36 + csp) ^ x]     = __builtin_amdgcn_perm(w1[i], w0[i], 0x05040100u);
      vt[((d+1)*36 + csp) ^ x] = __builtin_amdgcn_perm(w1[i], w0[i], 0x07060302u);
    }
  };

  // prologue: epoch 0 (tiles ts=0,1), then preload epoch 1's tiles
  kload(ts);                    // tiles 0,1 (ktmax >= 16, both valid)
  stage(ts);
  if (2 + ts <= ktmax) kload(2 + ts);
  __syncthreads();

  for (int e = 0; e < E; ++e) {
    if (e + 1 < E && 2*(e+1) + ts <= ktmax) {
      stage(((e+1) & 1) * 2 + ts);                // write OTHER pair
      if (e + 2 < E && 2*(e+2) + ts <= ktmax) kload(2*(e+2) + ts);
    }
    const int kt = 2*e + par;
    if (kt <= qt) {
      const half_t* ksb = &smem[(e & 1) * 2 + par][0];
      const uint32_t* vt32 = reinterpret_cast<const uint32_t*>(ksb + 4608);
      // ---- QK^T: S^T[key 0..63][q = l31] ----
      f32x16 sacc[2];
      sacc[0] = (f32x16)(0.f); sacc[1] = (f32x16)(0.f);
      __builtin_amdgcn_s_setprio(1);
      #pragma unroll
      for (int kb = 0; kb < 2; ++kb)
        #pragma unroll
        for (int kk = 0; kk < 4; ++kk) {
          const half8 a = *reinterpret_cast<const half8*>(
              ksb + (kb*32 + l31)*72 + kk*16 + lh*8);
          sacc[kb] = __builtin_amdgcn_mfma_f32_32x32x16_f16(a, qreg[kk], sacc[kb], 0, 0, 0);
        }
      __builtin_amdgcn_s_setprio(0);
      // ---- softmax (keys in regs: key = kb*32 + (r&3)+8*(r>>2)+4*lh) ----
      float sv[2][16]; float tm = -3.0e38f;
      const bool diag = (kt == qt);
      const int qloc = rh * 32 + l31;
      #pragma unroll
      for (int kb = 0; kb < 2; ++kb)
        #pragma unroll
        for (int r = 0; r < 16; ++r) {
          float s = sacc[kb][r];
          if (diag && (kb*32 + (r&3) + 8*(r>>2) + 4*lh > qloc)) s = -1e30f;
          sv[kb][r] = s;
          tm = fmaxf(tm, s);
        }
      tm = fmaxf(tm, __shfl_xor(tm, 32));
      if (!__all(tm <= m + DEFER_THR)) {
        const float mn = fmaxf(m, tm);
        const float alpha = __builtin_amdgcn_exp2f((m - mn) * LOG2E);
        yacc[0] *= alpha; yacc[1] *= alpha;
        lsum *= alpha;
        m = mn;
      }
      const float nm = -m * LOG2E;
      float rs = 0.f;
      #pragma unroll
      for (int kb = 0; kb < 2; ++kb)
        #pragma unroll
        for (int r = 0; r < 16; ++r) {
          sv[kb][r] = __builtin_amdgcn_exp2f(fmaf(sv[kb][r], LOG2E, nm));
          rs += sv[kb][r];
        }
      lsum += rs;
      // ---- pack P in-register ----
      uint32_t w[2][8];
      #pragma unroll
      for (int kb = 0; kb < 2; ++kb)
        #pragma unroll
        for (int r2 = 0; r2 < 8; ++r2)
          w[kb][r2] = pk_h2(sv[kb][2*r2], sv[kb][2*r2+1]);
      // ---- PV: yacc[db] += V^T[db] . P (B-frag = own regs, no LDS) ----
      __builtin_amdgcn_s_setprio(1);
      #pragma unroll
      for (int db = 0; db < 2; ++db)
        #pragma unroll
        for (int kb = 0; kb < 2; ++kb)
          #pragma unroll
          for (int kk = 0; kk < 2; ++kk) {
            const int gdw = (vbase[db] + kb*16 + kk*8) ^ vxr[db];
            const half8 va = *reinterpret_cast<const half8*>(vt32 + gdw);
            union { uint32_t u[4]; half8 h; } bf;
            bf.u[0] = w[kb][4*kk + 0]; bf.u[1] = w[kb][4*kk + 1];
            bf.u[2] = w[kb][4*kk + 2]; bf.u[3] = w[kb][4*kk + 3];
            yacc[db] = __builtin_amdgcn_mfma_f32_32x32x16_f16(va, bf.h, yacc[db], 0, 0, 0);
          }
      __builtin_amdgcn_s_setprio(0);
    }
    __syncthreads();
  }

  // ---- merge kt-parities through LDS (K/V buffers dead; r12-verified) ----
  float* mb = reinterpret_cast<float*>(&smem[0][0]);
  const int pr = tile * 2 + rh;                 // partner pair id 0..3
  float* yb = mb + pr * 2176;
  if (par == 0) {
    #pragma unroll
    for (int db = 0; db < 2; ++db)
      #pragma unroll
      for (int r = 0; r < 16; ++r)
        yb[(db*16 + r) * 64 + lane] = yacc[db][r];
    yb[2048 + lane] = m;
    yb[2112 + lane] = lsum;
  }
  __syncthreads();
  if (par == 1) {
    const float me = yb[2048 + lane];
    const float le = yb[2112 + lane];
    const float M = fmaxf(m, me);
    const float ae = __builtin_amdgcn_exp2f((me - M) * LOG2E);
    const float ao = __builtin_amdgcn_exp2f((m - M) * LOG2E);
    float lt = le * ae + lsum * ao;
    lt += __shfl_xor(lt, 32);
    const float inv = 1.0f / lt;
    float yv[2][16];
    #pragma unroll
    for (int db = 0; db < 2; ++db)
      #pragma unroll
      for (int r = 0; r < 16; ++r)
        yv[db][r] = (yb[(db*16 + r) * 64 + lane] * ae + yacc[db][r] * ao) * inv;
    // epilogue: per-db (=32-dim group) fake-quant, write fp16 qdq values
    half_t* yp = y16 + qrow * CC + h * HD;
    #pragma unroll
    for (int db = 0; db < 2; ++db) {
      float am = 0.f;
      #pragma unroll
      for (int r = 0; r < 16; ++r) am = fmaxf(am, fabsf(yv[db][r]));
      am = fmaxf(am, __shfl_xor(am, 32));
      const float s = fmaxf(am / 127.0f, 1e-8f);
      const float qi = 1.0f / s;
      #pragma unroll
      for (int t = 0; t < 4; ++t) {
        union { half_t h4[4]; uint64_t u; } pk;
        #pragma unroll
        for (int rr = 0; rr < 4; ++rr) {
          float q = fminf(fmaxf(rintf(yv[db][4*t + rr] * qi), -127.f), 127.f);
          pk.h4[rr] = (half_t)(q * s);
        }
        *reinterpret_cast<uint64_t*>(yp + db*32 + 8*t + 4*lh) = pk.u;
      }
    }
  }
}

// ---------------------------------------------------------------------------
// residual (x + proj_part0 + proj_part1) + stats + output quantization.
// ---------------------------------------------------------------------------
__global__ __launch_bounds__(256) void k_final(
    const float* __restrict__ x, const half_t* __restrict__ p0,
    const half_t* __restrict__ p1,
    float* __restrict__ out_fpx, float* __restrict__ out_qo, float* __restrict__ out_so,
    float* __restrict__ out_mean, float* __restrict__ out_rstd) {
  __shared__ float red[16];
  int row = blockIdx.x;
  int tid = threadIdx.x;
  size_t base = (size_t)row * CC + tid * 4;
  float4 xv = *reinterpret_cast<const float4*>(x + base);
  union { uint64_t u; half_t h[4]; } pa, pb;
  pa.u = *reinterpret_cast<const uint64_t*>(p0 + base);
  pb.u = *reinterpret_cast<const uint64_t*>(p1 + base);
  float4 f;
  f.x = xv.x + (float)pa.h[0] + (float)pb.h[0];
  f.y = xv.y + (float)pa.h[1] + (float)pb.h[1];
  f.z = xv.z + (float)pa.h[2] + (float)pb.h[2];
  f.w = xv.w + (float)pa.h[3] + (float)pb.h[3];
  *reinterpret_cast<float4*>(out_fpx + base) = f;
  float sum = f.x + f.y + f.z + f.w;
  float sq  = f.x*f.x + f.y*f.y + f.z*f.z + f.w*f.w;
  #pragma unroll
  for (int off = 1; off < 64; off <<= 1) {
    sum += __shfl_xor(sum, off);
    sq  += __shfl_xor(sq, off);
  }
  int wid = tid >> 6, lane = tid & 63;
  if (lane == 0) { red[wid] = sum; red[8 + wid] = sq; }
  __syncthreads();
  if (tid == 0) {
    float s4 = red[0] + red[1] + red[2] + red[3];
    float q4 = red[8] + red[9] + red[10] + red[11];
    float mu = s4 * (1.0f / CC);
    float var = q4 * (1.0f / CC) - mu * mu;
    out_mean[row] = mu;
    out_rstd[row] = 1.0f / sqrtf(var + 1e-5f);
  }
  float amax = fmaxf(fmaxf(fabsf(f.x), fabsf(f.y)), fmaxf(fabsf(f.z), fabsf(f.w)));
  #pragma unroll
  for (int off = 1; off < 8; off <<= 1) amax = fmaxf(amax, __shfl_xor(amax, off, 8));
  float s = fmaxf(amax / 127.0f, 1e-8f);
  int g = tid >> 3, li = tid & 7;
  if (li == 0) out_so[row * NG + g] = s;
  float4 qo;
  qo.x = fminf(fmaxf(rintf(f.x / s), -127.f), 127.f);
  qo.y = fminf(fmaxf(rintf(f.y / s), -127.f), 127.f);
  qo.z = fminf(fmaxf(rintf(f.z / s), -127.f), 127.f);
  qo.w = fminf(fmaxf(rintf(f.w / s), -127.f), 127.f);
  *reinterpret_cast<float4*>(out_qo + base) = qo;
}

// ---------------------------------------------------------------------------
extern "C" void kernel_launch(void* const* d_in, const int* in_sizes, int n_in,
                              void* d_out, int out_size, void* d_ws, size_t ws_size,
                              hipStream_t stream) {
  const float* x    = (const float*)d_in[0];
  const int*   qx   = (const int*)d_in[1];
  const float* sx   = (const float*)d_in[2];
  const float* mean = (const float*)d_in[3];
  const float* rstd = (const float*)d_in[4];
  const float* lnw  = (const float*)d_in[5];
  const float* w1   = (const float*)d_in[6];
  const float* w2   = (const float*)d_in[7];

  float* out = (float*)d_out;
  float* o_fpx  = out;
  float* o_qo   = o_fpx + (size_t)ROWS * CC;
  float* o_so   = o_qo  + (size_t)ROWS * CC;
  float* o_mean = o_so  + (size_t)ROWS * NG;
  float* o_rstd = o_mean + ROWS;

  size_t off = 0;
  char* wsb = (char*)d_ws;
  auto alloc = [&](size_t bytes) -> void* {
    void* p = wsb + off;
    off += (bytes + 255) & ~(size_t)255;
    return p;
  };
  half_t* h16   = (half_t*)alloc((size_t)ROWS * CC * 2);
  half_t* w116  = (half_t*)alloc((size_t)C3 * CC * 2);
  half_t* w216  = (half_t*)alloc((size_t)CC * CC * 2);
  half_t* qkv16 = (half_t*)alloc((size_t)ROWS * C3 * 2);
  half_t* y16   = (half_t*)alloc((size_t)ROWS * CC * 2);
  half_t* proj  = (half_t*)alloc((size_t)2 * ROWS * CC * 2);   // 2 K-slices

  // 1. weight fake-quant -> fp16 (both weights, one launch)
  k_qdq_w<<<(C3 * NG + CC * NG) / 256, 256, 0, stream>>>(w1, w2, w116, w216);
  // 2. LN + activation fake-quant -> fp16
  k_qh<<<(ROWS * NG) / 256, 256, 0, stream>>>(qx, sx, mean, rstd, lnw, h16);
  // 3. qkv = h @ w1^T  (fp16 MFMA, dbuf 2-phase, XCD-swizzled)
  k_gemm16<half_t><<<dim3(C3 / 128, ROWS / 128, 1), 256, 0, stream>>>(
      h16, w116, qkv16, C3, C3 / 128, (C3 / 128) * (ROWS / 128) / 8, 1024);
  // 4. causal SDPA (32x32 MFMA, in-reg P, two tiles/epoch, sequential kt)
  k_attn32<<<dim3(BB * NH, 16), 512, 0, stream>>>(qkv16, y16);
  // 5. proj = y @ w2^T  (fp16 MFMA, dbuf 2-phase, split-K=2)
  k_gemm16<half_t><<<dim3(CC / 128, ROWS / 128, 2), 256, 0, stream>>>(
      y16, w216, proj, CC, CC / 128, (CC / 128) * (ROWS / 128) / 8, 512);
  // 6. residual (x + p0 + p1) + stats + output quant
  k_final<<<ROWS, 256, 0, stream>>>(x, proj, proj + (size_t)ROWS * CC,
                                    o_fpx, o_qo, o_so, o_mean, o_rstd);
}

// Round 16
// 123.468 us; speedup vs baseline: 1.6827x; 1.2703x over previous
//
#include <hip/hip_runtime.h>
#include <stdint.h>

// Problem constants
#define BB 2
#define TT 2048
#define CC 1024
#define NH 16
#define HD 64
#define NG 32              // groups per C row (group size 32)
#define ROWS (BB*TT)       // 4096
#define C3 (3*CC)          // 3072

typedef _Float16 half_t;
typedef __attribute__((ext_vector_type(8))) _Float16 half8;
typedef __attribute__((ext_vector_type(2))) __fp16 fp16x2;
typedef __attribute__((ext_vector_type(4))) float f32x4;

#define GLDS16(g, l) __builtin_amdgcn_global_load_lds( \
    (__attribute__((address_space(1))) void*)(g), \
    (__attribute__((address_space(3))) void*)(l), 16, 0, 0)

#define LOG2E 1.44269504f
#define DEFER_THR 5.5451774f   /* 8 / log2(e) */

__device__ __forceinline__ uint32_t pk_h2(float a, float b) {
  union { fp16x2 h; uint32_t u; } cv;
  cv.h = __builtin_amdgcn_cvt_pkrtz(a, b);
  return cv.u;
}

// ---------------------------------------------------------------------------
// merged pre-pass: blocks [0,512) = weight fake-quant (w1|w2 -> fp16 qdq);
// blocks [512,1024) = dequant(qx)+LN+fake-quant -> fp16 h.
// Both paths byte-identical to the r11-passing k_qdq_w / k_qh.
// ---------------------------------------------------------------------------
__global__ void k_pre(const float* __restrict__ w1, const float* __restrict__ w2,
                      half_t* __restrict__ o1, half_t* __restrict__ o2,
                      const int* __restrict__ qx, const float* __restrict__ sx,
                      const float* __restrict__ mean, const float* __restrict__ rstd,
                      const float* __restrict__ lnw, half_t* __restrict__ h16) {
  const int blk = blockIdx.x;
  if (blk < 512) {
    // ---- weight fake-quant ----
    int g = blk * blockDim.x + threadIdx.x;
    const float* src; half_t* dst; int gl;
    if (g < C3 * NG) { src = w1; dst = o1; gl = g; }
    else             { src = w2; dst = o2; gl = g - C3 * NG; }
    const float4* p = reinterpret_cast<const float4*>(src + (size_t)gl * 32);
    float v[32]; float amax = 0.f;
    #pragma unroll
    for (int i = 0; i < 8; ++i) {
      float4 t = p[i];
      v[4*i] = t.x; v[4*i+1] = t.y; v[4*i+2] = t.z; v[4*i+3] = t.w;
      amax = fmaxf(amax, fmaxf(fmaxf(fabsf(t.x), fabsf(t.y)), fmaxf(fabsf(t.z), fabsf(t.w))));
    }
    float s = fmaxf(amax / 127.0f, 1e-8f);
    half_t* o = dst + (size_t)gl * 32;
    #pragma unroll
    for (int c = 0; c < 4; ++c) {
      half8 ov;
      #pragma unroll
      for (int jj = 0; jj < 8; ++jj) {
        float q = fminf(fmaxf(rintf(v[c*8+jj] / s), -127.f), 127.f);
        ov[jj] = (half_t)(q * s);
      }
      *reinterpret_cast<half8*>(o + c*8) = ov;
    }
  } else {
    // ---- LN + activation fake-quant ----
    int g = (blk - 512) * blockDim.x + threadIdx.x;
    int row = g >> 5, grp = g & 31;
    float sxv = sx[g];
    float mu = mean[row], rs = rstd[row];
    const int4* qp = reinterpret_cast<const int4*>(qx + (size_t)row * CC + grp * 32);
    const float4* wp = reinterpret_cast<const float4*>(lnw + grp * 32);
    float v[32]; float amax = 0.f;
    #pragma unroll
    for (int i = 0; i < 8; ++i) {
      int4 qv = qp[i]; float4 wv = wp[i];
      float h0 = ((float)qv.x * sxv - mu) * rs * wv.x;
      float h1 = ((float)qv.y * sxv - mu) * rs * wv.y;
      float h2 = ((float)qv.z * sxv - mu) * rs * wv.z;
      float h3 = ((float)qv.w * sxv - mu) * rs * wv.w;
      v[4*i] = h0; v[4*i+1] = h1; v[4*i+2] = h2; v[4*i+3] = h3;
      amax = fmaxf(amax, fmaxf(fmaxf(fabsf(h0), fabsf(h1)), fmaxf(fabsf(h2), fabsf(h3))));
    }
    float s = fmaxf(amax / 127.0f, 1e-8f);
    half_t* o = h16 + (size_t)row * CC + grp * 32;
    #pragma unroll
    for (int c = 0; c < 4; ++c) {
      half8 ov;
      #pragma unroll
      for (int jj = 0; jj < 8; ++jj) {
        float q = fminf(fmaxf(rintf(v[c*8+jj] / s), -127.f), 127.f);
        ov[jj] = (half_t)(q * s);
      }
      *reinterpret_cast<half8*>(o + c*8) = ov;
    }
  }
}

// ---------------------------------------------------------------------------
// fp16 MFMA GEMM (r11, passing): 128x128 tile, BK=32 double-buffered,
// XCD-bijective swizzle, split-K via blockIdx.z.
// ---------------------------------------------------------------------------
template<typename TO>
__global__ __launch_bounds__(256) void k_gemm16(const half_t* __restrict__ A,
                                                const half_t* __restrict__ B,
                                                TO* __restrict__ Out, int N,
                                                int gx, int cpx, int klen) {
  __shared__ __align__(16) half_t As[2][128*32];
  __shared__ __align__(16) half_t Bs[2][128*32];
  const int tid = threadIdx.x;
  const int wave = tid >> 6, lane = tid & 63;
  const int l15 = lane & 15, lg = lane >> 4;
  const int flat = blockIdx.y * gx + blockIdx.x;
  const int swz = (flat & 7) * cpx + (flat >> 3);
  const int m0 = (swz / gx) * 128, n0 = (swz % gx) * 128;
  const int kbeg = blockIdx.z * klen;
  TO* out = Out + (size_t)blockIdx.z * ROWS * N;
  const int wm = (wave >> 1) * 64, wn = (wave & 1) * 64;
  f32x4 acc[4][4];
  #pragma unroll
  for (int i = 0; i < 4; ++i)
    #pragma unroll
    for (int jj = 0; jj < 4; ++jj) acc[i][jj] = f32x4{0.f, 0.f, 0.f, 0.f};
  const int srow = lane >> 2;
  const int scol = (lane & 3) * 8;
  const int seg0 = wave * 2;
  auto stage = [&](int buf, int k0) {
    #pragma unroll
    for (int s = 0; s < 2; ++s) {
      const int seg = seg0 + s;
      GLDS16(A + (size_t)(m0 + seg*16 + srow) * 1024 + k0 + scol, &As[buf][0] + seg*512);
      GLDS16(B + (size_t)(n0 + seg*16 + srow) * 1024 + k0 + scol, &Bs[buf][0] + seg*512);
    }
  };
  stage(0, kbeg);
  __syncthreads();
  int cur = 0;
  for (int k0 = kbeg; k0 < kbeg + klen; k0 += 32) {
    if (k0 + 32 < kbeg + klen) stage(cur ^ 1, k0 + 32);
    half8 af[4], bf[4];
    #pragma unroll
    for (int i = 0; i < 4; ++i) {
      af[i] = *reinterpret_cast<const half8*>(&As[cur][0] + (wm + i*16 + l15)*32 + lg*8);
      bf[i] = *reinterpret_cast<const half8*>(&Bs[cur][0] + (wn + i*16 + l15)*32 + lg*8);
    }
    #pragma unroll
    for (int mi = 0; mi < 4; ++mi)
      #pragma unroll
      for (int ni = 0; ni < 4; ++ni)
        acc[mi][ni] = __builtin_amdgcn_mfma_f32_16x16x32_f16(af[mi], bf[ni], acc[mi][ni], 0, 0, 0);
    __syncthreads();
    cur ^= 1;
  }
  const int crow = m0 + wm + lg * 4;
  const int ccol = n0 + wn + l15;
  #pragma unroll
  for (int mi = 0; mi < 4; ++mi)
    #pragma unroll
    for (int ni = 0; ni < 4; ++ni)
      #pragma unroll
      for (int r = 0; r < 4; ++r)
        out[(size_t)(crow + mi*16 + r) * N + ccol + ni*16] = (TO)acc[mi][ni][r];
}

// ---------------------------------------------------------------------------
// MFMA flash attention (EXACT r9/r11 structure — passed at 46.5us).
// Paired q-tiles {j, 31-j}, 512 threads / 8 waves: waves 0-3 tile A(=j),
// waves 4-7 tile B(=31-j) concurrently. Double-buffered K/V staging.
// ---------------------------------------------------------------------------
__global__ __launch_bounds__(512, 4) void k_attn16(const half_t* __restrict__ qkv,
                                                   half_t* __restrict__ y16) {
  __shared__ __align__(16) half_t Ks[2][64*72];
  __shared__ __align__(16) half_t Vt[2][64*72];   // XOR-swizzled [dim][key-pair]
  __shared__ __align__(16) half_t Ps[8][16*72];
  const int tid = threadIdx.x;
  const int wave = tid >> 6, lane = tid & 63;
  const int l15 = lane & 15, lg = lane >> 4;
  const int w4 = wave & 3;
  const int bh = blockIdx.x, b = bh >> 4, h = bh & 15;
  const int j = blockIdx.y;
  const int qtB = 31 - j;
  const int qt = (wave >> 2) ? qtB : j;    // this wave's q-tile

  // Q fragment, prescaled by 1/sqrt(hd)=0.125 (exact in fp16)
  const size_t row = (size_t)(b * TT + qt * 64 + w4 * 16 + l15);
  const half_t* qp = qkv + row * C3 + h * HD + lg * 8;
  const half8 q0 = *reinterpret_cast<const half8*>(qp)      * (half_t)0.125f;
  const half8 q1 = *reinterpret_cast<const half8*>(qp + 32) * (half_t)0.125f;

  float m = -3.0e38f;
  f32x4 yacc[4];
  f32x4 lacc = f32x4{0,0,0,0};
  #pragma unroll
  for (int n = 0; n < 4; ++n) yacc[n] = f32x4{0,0,0,0};

  // staging maps (512 threads)
  const int sj = tid >> 3, sc = (tid & 7) * 8;       // K: key sj, dims sc..sc+7
  const int vkp = tid >> 4, vd0 = (tid & 15) * 4;    // V: keys 2vkp,2vkp+1, dims vd0..+3
  const int vxor = ((vd0 >> 3) & 7) << 2;            // dword-index XOR (16B granular)
  const int pxor = (l15 & 3) << 3;                   // P dword-offset XOR
  half_t* pw = &Ps[wave][0];

  // precomputed V^T read dword offsets (relative to buffer base)
  int vdw0[4], vdw1[4];
  #pragma unroll
  for (int n = 0; n < 4; ++n) {
    const int d = n*16 + l15;
    const int x = ((n*2 + (l15 >> 3)) & 7) << 2;
    vdw0[n] = (d*36 + lg*4) ^ x;
    vdw1[n] = (d*36 + 16 + lg*4) ^ x;
  }

  half8 ones8;
  #pragma unroll
  for (int i = 0; i < 8; ++i) ones8[i] = (half_t)1.0f;

  // K/V prefetch registers
  half8 k0r; uint2 u0r, u1r;
  const half_t* kvb = qkv + ((size_t)b * TT) * C3 + CC + h * HD;
  auto kload = [&](int kt) {
    const half_t* kp = kvb + (size_t)(kt*64 + sj) * C3 + sc;
    k0r = *reinterpret_cast<const half8*>(kp);
    const half_t* vp = kvb + (size_t)(kt*64 + vkp*2) * C3 + CC + vd0;
    u0r = *reinterpret_cast<const uint2*>(vp);
    u1r = *reinterpret_cast<const uint2*>(vp + C3);
  };
  auto stage = [&](int buf) {
    *reinterpret_cast<half8*>(&Ks[buf][0] + sj*72 + sc) = k0r;
    uint32_t* vt32 = reinterpret_cast<uint32_t*>(&Vt[buf][0]);
    vt32[((vd0+0)*36 + vkp) ^ vxor] = __builtin_amdgcn_perm(u1r.x, u0r.x, 0x05040100u);
    vt32[((vd0+1)*36 + vkp) ^ vxor] = __builtin_amdgcn_perm(u1r.x, u0r.x, 0x07060302u);
    vt32[((vd0+2)*36 + vkp) ^ vxor] = __builtin_amdgcn_perm(u1r.y, u0r.y, 0x05040100u);
    vt32[((vd0+3)*36 + vkp) ^ vxor] = __builtin_amdgcn_perm(u1r.y, u0r.y, 0x07060302u);
  };

  kload(0);
  stage(0);
  kload(1);                     // qtB >= 16 always, safe
  __syncthreads();
  for (int kt = 0; kt <= qtB; ++kt) {
    const int cur = kt & 1;
    if (kt < qtB) {
      stage(cur ^ 1);           // write OTHER buffer: overlaps compute of cur
      if (kt + 2 <= qtB) kload(kt + 2);
    }
    if (kt <= qt) {
      const half_t* ksb = &Ks[cur][0];
      const uint32_t* vt32 = reinterpret_cast<const uint32_t*>(&Vt[cur][0]);
      // ---- QK^T ----
      f32x4 sacc[4];
      __builtin_amdgcn_s_setprio(1);
      #pragma unroll
      for (int kg = 0; kg < 4; ++kg) {
        const half8 a0 = *reinterpret_cast<const half8*>(ksb + (kg*16 + l15)*72 + lg*8);
        const half8 a1 = *reinterpret_cast<const half8*>(ksb + (kg*16 + l15)*72 + lg*8 + 32);
        f32x4 t = f32x4{0,0,0,0};
        t = __builtin_amdgcn_mfma_f32_16x16x32_f16(a0, q0, t, 0, 0, 0);
        t = __builtin_amdgcn_mfma_f32_16x16x32_f16(a1, q1, t, 0, 0, 0);
        sacc[kg] = t;
      }
      __builtin_amdgcn_s_setprio(0);
      // ---- softmax ----
      float sv[16]; float tm = -3.0e38f;
      const bool diag = (kt == qt);
      #pragma unroll
      for (int kg = 0; kg < 4; ++kg)
        #pragma unroll
        for (int r = 0; r < 4; ++r) {
          float s = sacc[kg][r];
          if (diag && (kg*16 + lg*4 + r > w4*16 + l15)) s = -1e30f;
          sv[kg*4 + r] = s;
          tm = fmaxf(tm, s);
        }
      tm = fmaxf(tm, __shfl_xor(tm, 16));
      tm = fmaxf(tm, __shfl_xor(tm, 32));
      if (!__all(tm <= m + DEFER_THR)) {
        const float mn = fmaxf(m, tm);
        const float alpha = __builtin_amdgcn_exp2f((m - mn) * LOG2E);
        #pragma unroll
        for (int n = 0; n < 4; ++n) yacc[n] *= alpha;
        lacc *= alpha;
        m = mn;
      }
      const float nm = -m * LOG2E;
      #pragma unroll
      for (int i = 0; i < 16; ++i)
        sv[i] = __builtin_amdgcn_exp2f(fmaf(sv[i], LOG2E, nm));
      // P -> wave-private LDS, XOR-swizzled (full-bank spread)
      uint32_t* prow = reinterpret_cast<uint32_t*>(pw) + l15*36;
      #pragma unroll
      for (int kg = 0; kg < 4; ++kg) {
        uint2 pr;
        pr.x = pk_h2(sv[kg*4 + 0], sv[kg*4 + 1]);
        pr.y = pk_h2(sv[kg*4 + 2], sv[kg*4 + 3]);
        *reinterpret_cast<uint2*>(prow + ((kg*8 + lg*2) ^ pxor)) = pr;
      }
      __builtin_amdgcn_sched_barrier(0);
      const half8 pb0 = *reinterpret_cast<const half8*>(
          pw + (l15*36 + ((lg*4) ^ pxor)) * 2);
      const half8 pb1 = *reinterpret_cast<const half8*>(
          pw + (l15*36 + ((16 + lg*4) ^ pxor)) * 2);
      // ---- PV + row-sum ----
      __builtin_amdgcn_s_setprio(1);
      #pragma unroll
      for (int n = 0; n < 4; ++n) {
        const half8 va0 = *reinterpret_cast<const half8*>(vt32 + vdw0[n]);
        const half8 va1 = *reinterpret_cast<const half8*>(vt32 + vdw1[n]);
        yacc[n] = __builtin_amdgcn_mfma_f32_16x16x32_f16(va0, pb0, yacc[n], 0, 0, 0);
        yacc[n] = __builtin_amdgcn_mfma_f32_16x16x32_f16(va1, pb1, yacc[n], 0, 0, 0);
      }
      lacc = __builtin_amdgcn_mfma_f32_16x16x32_f16(ones8, pb0, lacc, 0, 0, 0);
      lacc = __builtin_amdgcn_mfma_f32_16x16x32_f16(ones8, pb1, lacc, 0, 0, 0);
      __builtin_amdgcn_s_setprio(0);
    }
    __syncthreads();
  }

  // epilogue: normalize + fused group-32 fake-quant, write fp16 qdq values
  const float inv = 1.0f / lacc[0];
  float v[16];
  #pragma unroll
  for (int n = 0; n < 4; ++n)
    #pragma unroll
    for (int r = 0; r < 4; ++r) v[n*4 + r] = yacc[n][r] * inv;
  half_t* yp = y16 + row * CC + h * HD;
  #pragma unroll
  for (int g = 0; g < 2; ++g) {
    float am = 0.f;
    #pragma unroll
    for (int t = 0; t < 8; ++t) am = fmaxf(am, fabsf(v[g*8 + t]));
    am = fmaxf(am, __shfl_xor(am, 16));
    am = fmaxf(am, __shfl_xor(am, 32));
    const float s = fmaxf(am / 127.0f, 1e-8f);
    const float qi = 1.0f / s;
    #pragma unroll
    for (int nn = 0; nn < 2; ++nn) {
      const int n = g*2 + nn;
      union { half_t h4[4]; uint64_t u; } pk;
      #pragma unroll
      for (int r = 0; r < 4; ++r) {
        float q = fminf(fmaxf(rintf(v[n*4 + r] * qi), -127.f), 127.f);
        pk.h4[r] = (half_t)(q * s);
      }
      *reinterpret_cast<uint64_t*>(yp + n*16 + lg*4) = pk.u;
    }
  }
}

// ---------------------------------------------------------------------------
// residual (x + proj_part0 + proj_part1) + stats + output quantization.
// ---------------------------------------------------------------------------
__global__ __launch_bounds__(256) void k_final(
    const float* __restrict__ x, const half_t* __restrict__ p0,
    const half_t* __restrict__ p1,
    float* __restrict__ out_fpx, float* __restrict__ out_qo, float* __restrict__ out_so,
    float* __restrict__ out_mean, float* __restrict__ out_rstd) {
  __shared__ float red[16];
  int row = blockIdx.x;
  int tid = threadIdx.x;
  size_t base = (size_t)row * CC + tid * 4;
  float4 xv = *reinterpret_cast<const float4*>(x + base);
  union { uint64_t u; half_t h[4]; } pa, pb;
  pa.u = *reinterpret_cast<const uint64_t*>(p0 + base);
  pb.u = *reinterpret_cast<const uint64_t*>(p1 + base);
  float4 f;
  f.x = xv.x + (float)pa.h[0] + (float)pb.h[0];
  f.y = xv.y + (float)pa.h[1] + (float)pb.h[1];
  f.z = xv.z + (float)pa.h[2] + (float)pb.h[2];
  f.w = xv.w + (float)pa.h[3] + (float)pb.h[3];
  *reinterpret_cast<float4*>(out_fpx + base) = f;
  float sum = f.x + f.y + f.z + f.w;
  float sq  = f.x*f.x + f.y*f.y + f.z*f.z + f.w*f.w;
  #pragma unroll
  for (int off = 1; off < 64; off <<= 1) {
    sum += __shfl_xor(sum, off);
    sq  += __shfl_xor(sq, off);
  }
  int wid = tid >> 6, lane = tid & 63;
  if (lane == 0) { red[wid] = sum; red[8 + wid] = sq; }
  __syncthreads();
  if (tid == 0) {
    float s4 = red[0] + red[1] + red[2] + red[3];
    float q4 = red[8] + red[9] + red[10] + red[11];
    float mu = s4 * (1.0f / CC);
    float var = q4 * (1.0f / CC) - mu * mu;
    out_mean[row] = mu;
    out_rstd[row] = 1.0f / sqrtf(var + 1e-5f);
  }
  float amax = fmaxf(fmaxf(fabsf(f.x), fabsf(f.y)), fmaxf(fabsf(f.z), fabsf(f.w)));
  #pragma unroll
  for (int off = 1; off < 8; off <<= 1) amax = fmaxf(amax, __shfl_xor(amax, off, 8));
  float s = fmaxf(amax / 127.0f, 1e-8f);
  int g = tid >> 3, li = tid & 7;
  if (li == 0) out_so[row * NG + g] = s;
  float4 qo;
  qo.x = fminf(fmaxf(rintf(f.x / s), -127.f), 127.f);
  qo.y = fminf(fmaxf(rintf(f.y / s), -127.f), 127.f);
  qo.z = fminf(fmaxf(rintf(f.z / s), -127.f), 127.f);
  qo.w = fminf(fmaxf(rintf(f.w / s), -127.f), 127.f);
  *reinterpret_cast<float4*>(out_qo + base) = qo;
}

// ---------------------------------------------------------------------------
extern "C" void kernel_launch(void* const* d_in, const int* in_sizes, int n_in,
                              void* d_out, int out_size, void* d_ws, size_t ws_size,
                              hipStream_t stream) {
  const float* x    = (const float*)d_in[0];
  const int*   qx   = (const int*)d_in[1];
  const float* sx   = (const float*)d_in[2];
  const float* mean = (const float*)d_in[3];
  const float* rstd = (const float*)d_in[4];
  const float* lnw  = (const float*)d_in[5];
  const float* w1   = (const float*)d_in[6];
  const float* w2   = (const float*)d_in[7];

  float* out = (float*)d_out;
  float* o_fpx  = out;
  float* o_qo   = o_fpx + (size_t)ROWS * CC;
  float* o_so   = o_qo  + (size_t)ROWS * CC;
  float* o_mean = o_so  + (size_t)ROWS * NG;
  float* o_rstd = o_mean + ROWS;

  size_t off = 0;
  char* wsb = (char*)d_ws;
  auto alloc = [&](size_t bytes) -> void* {
    void* p = wsb + off;
    off += (bytes + 255) & ~(size_t)255;
    return p;
  };
  half_t* h16   = (half_t*)alloc((size_t)ROWS * CC * 2);
  half_t* w116  = (half_t*)alloc((size_t)C3 * CC * 2);
  half_t* w216  = (half_t*)alloc((size_t)CC * CC * 2);
  half_t* qkv16 = (half_t*)alloc((size_t)ROWS * C3 * 2);
  half_t* y16   = (half_t*)alloc((size_t)ROWS * CC * 2);
  half_t* proj  = (half_t*)alloc((size_t)2 * ROWS * CC * 2);   // 2 K-slices

  // 1. merged pre-pass: weight fake-quant + LN/activation fake-quant
  k_pre<<<1024, 256, 0, stream>>>(w1, w2, w116, w216, qx, sx, mean, rstd, lnw, h16);
  // 2. qkv = h @ w1^T  (fp16 MFMA, dbuf 2-phase, XCD-swizzled)
  k_gemm16<half_t><<<dim3(C3 / 128, ROWS / 128, 1), 256, 0, stream>>>(
      h16, w116, qkv16, C3, C3 / 128, (C3 / 128) * (ROWS / 128) / 8, 1024);
  // 3. causal SDPA (r9 kernel: dbuf K/V, concurrent paired q-tiles)
  k_attn16<<<dim3(BB * NH, 16), 512, 0, stream>>>(qkv16, y16);
  // 4. proj = y @ w2^T  (fp16 MFMA, dbuf 2-phase, split-K=2)
  k_gemm16<half_t><<<dim3(CC / 128, ROWS / 128, 2), 256, 0, stream>>>(
      y16, w216, proj, CC, CC / 128, (CC / 128) * (ROWS / 128) / 8, 512);
  // 5. residual (x + p0 + p1) + stats + output quant
  k_final<<<ROWS, 256, 0, stream>>>(x, proj, proj + (size_t)ROWS * CC,
                                    o_fpx, o_qo, o_so, o_mean, o_rstd);
}